// Round 10
// baseline (690.470 us; speedup 1.0000x reference)
//
#include <hip/hip_runtime.h>

// LSTM predictor: B=1024, T=1024, H=51, input=1. Sequential recurrence.
//
// Round 10: round-9 structure (single wave/batch, 104 f16-packed weight
// VGPRs, double-f16 h for fp32-grade numerics, DPP row_shl:1 pair pack,
// no barriers) with ONE change: all 52 readlanes (26 hi-pairs + 26
// lo-pairs) are batched UPFRONT into SGPR arrays before any dot2 issues.
//   Round-9 lesson: v_readlane writes an SGPR; a VALU read of that SGPR
//   within ~5 cyc takes mandatory wait states. 52 immediate-use readlanes
//   cost ~260 cyc/step of hazard stalls (measured busy 1342 vs counted
//   ~660). Batching puts >=50 instructions between each readlane and its
//   first consumer -> zero hazard stalls; the dot phase is then a clean
//   208-dot2 block in 4 independent chains (same-chain gap 8 cyc).
// fc output staged in stride-65 LDS, reduced every 64 steps. x dbuffered.

#define HID 51
#define SEQ_T 1024
#define NPAIR 26

typedef _Float16 f16;
typedef unsigned int u32;
typedef __attribute__((ext_vector_type(2))) _Float16 half2_t;

static __device__ __forceinline__ float lane_bcast(float v, int lane) {
    return __int_as_float(__builtin_amdgcn_readlane(__float_as_int(v), lane));
}
static __device__ __forceinline__ float fast_sigmoid(float x) {
    float e = __builtin_amdgcn_exp2f(x * -1.44269504088896340736f);
    return __builtin_amdgcn_rcpf(1.0f + e);
}
static __device__ __forceinline__ float fast_tanh(float x) {
    float e = __builtin_amdgcn_exp2f(x * 2.88539008177792681472f);
    return 1.0f - 2.0f * __builtin_amdgcn_rcpf(e + 1.0f);
}

__global__ __launch_bounds__(64)
__attribute__((amdgpu_waves_per_eu(1, 1)))
void lstm_solo_kernel(
    const float* __restrict__ x,      // [B, T]
    const float* __restrict__ W_ih,   // [4H, 1]
    const float* __restrict__ W_hh,   // [4H, H]
    const float* __restrict__ b_ih,   // [4H]
    const float* __restrict__ b_hh,   // [4H]
    const float* __restrict__ fc_w,   // [1, H]
    const float* __restrict__ fc_b,   // [1]
    float* __restrict__ out)          // [B, T]
{
    const int b = blockIdx.x;
    const int l = threadIdx.x;
    const bool act = (l < HID);

    __shared__ float pbuf[64][65];  // fc staging; stride 65 conflict-free

    // ---- pack all 4 gate-rows of W_hh into f16 pairs (104 VGPRs) ----
    u32 w0[NPAIR], w1[NPAIR], w2[NPAIR], w3[NPAIR];
#pragma unroll
    for (int p = 0; p < NPAIR; ++p) {
        float v00=0.f,v01=0.f,v10=0.f,v11=0.f,v20=0.f,v21=0.f,v30=0.f,v31=0.f;
        if (act) {
            const int k0 = 2 * p, k1 = 2 * p + 1;
            v00 = W_hh[(0 * HID + l) * HID + k0];
            v10 = W_hh[(1 * HID + l) * HID + k0];
            v20 = W_hh[(2 * HID + l) * HID + k0];
            v30 = W_hh[(3 * HID + l) * HID + k0];
            if (k1 < HID) {
                v01 = W_hh[(0 * HID + l) * HID + k1];
                v11 = W_hh[(1 * HID + l) * HID + k1];
                v21 = W_hh[(2 * HID + l) * HID + k1];
                v31 = W_hh[(3 * HID + l) * HID + k1];
            }
        }
        half2_t p0 = {(f16)v00, (f16)v01}, p1 = {(f16)v10, (f16)v11};
        half2_t p2 = {(f16)v20, (f16)v21}, p3 = {(f16)v30, (f16)v31};
        w0[p] = __builtin_bit_cast(u32, p0);
        w1[p] = __builtin_bit_cast(u32, p1);
        w2[p] = __builtin_bit_cast(u32, p2);
        w3[p] = __builtin_bit_cast(u32, p3);
        asm volatile("" : "+v"(w0[p]), "+v"(w1[p]), "+v"(w2[p]), "+v"(w3[p]));
    }
    float b0=0.f,b1=0.f,b2=0.f,b3=0.f, wx0=0.f,wx1=0.f,wx2=0.f,wx3=0.f, fcw=0.f;
    if (act) {
        b0 = b_ih[0 * HID + l] + b_hh[0 * HID + l];
        b1 = b_ih[1 * HID + l] + b_hh[1 * HID + l];
        b2 = b_ih[2 * HID + l] + b_hh[2 * HID + l];
        b3 = b_ih[3 * HID + l] + b_hh[3 * HID + l];
        wx0 = W_ih[0 * HID + l];
        wx1 = W_ih[1 * HID + l];
        wx2 = W_ih[2 * HID + l];
        wx3 = W_ih[3 * HID + l];
        fcw = fc_w[l];
    }
    const float fcb = fc_b[0];

    float h = 0.f, c = 0.f;
    float xv = x[b * SEQ_T + l];  // first 64-step chunk of input

#pragma unroll 1
    for (int t0 = 0; t0 < SEQ_T; t0 += 64) {
        // prefetch next chunk now; latency hides under 64 steps of compute
        const int tn = (t0 + 64 < SEQ_T) ? (t0 + 64) : t0;  // clamped re-read
        const float xnext = x[b * SEQ_T + tn + l];

#pragma unroll 1
        for (int i = 0; i < 64; ++i) {
            // ---- split h = hi + lo (double-f16), pair via DPP row_shl:1 ----
            const f16 hi_h = (f16)h;
            const float hi_f = (float)hi_h;
            const f16 lo_h = (f16)(h - hi_f);
            u32 own_hi = (u32)__builtin_bit_cast(unsigned short, hi_h);
            u32 own_lo = (u32)__builtin_bit_cast(unsigned short, lo_h);
            // row_shl:1 (0x101): lane n gets lane n+1 (verified round 8/9)
            u32 nb_hi = (u32)__builtin_amdgcn_update_dpp(
                0, (int)own_hi, 0x101, 0xf, 0xf, true);
            u32 nb_lo = (u32)__builtin_amdgcn_update_dpp(
                0, (int)own_lo, 0x101, 0xf, 0xf, true);
            const u32 hp2 = own_hi | (nb_hi << 16);  // (hi[2p], hi[2p+1])
            const u32 lp2 = own_lo | (nb_lo << 16);  // (lo[2p], lo[2p+1])

            // ---- phase 1: batch ALL readlanes into SGPRs (no consumers
            //      nearby -> no SGPR-after-VALU-write hazard stalls) ----
            int hs[NPAIR], ls[NPAIR];
#pragma unroll
            for (int p = 0; p < NPAIR; ++p)
                hs[p] = __builtin_amdgcn_readlane((int)hp2, 2 * p);
#pragma unroll
            for (int p = 0; p < NPAIR; ++p)
                ls[p] = __builtin_amdgcn_readlane((int)lp2, 2 * p);

            const float xt = lane_bcast(xv, i);
            float s0 = fmaf(xt, wx0, b0);
            float s1 = fmaf(xt, wx1, b1);
            float s2 = fmaf(xt, wx2, b2);
            float s3 = fmaf(xt, wx3, b3);

            // ---- phase 2: 208 dot2 in 4 independent chains ----
#pragma unroll
            for (int p = 0; p < NPAIR; ++p) {
                asm("v_dot2_f32_f16 %0, %2, %1, %0"
                    : "+v"(s0) : "v"(w0[p]), "s"(hs[p]));
                asm("v_dot2_f32_f16 %0, %2, %1, %0"
                    : "+v"(s1) : "v"(w1[p]), "s"(hs[p]));
                asm("v_dot2_f32_f16 %0, %2, %1, %0"
                    : "+v"(s2) : "v"(w2[p]), "s"(hs[p]));
                asm("v_dot2_f32_f16 %0, %2, %1, %0"
                    : "+v"(s3) : "v"(w3[p]), "s"(hs[p]));
                asm("v_dot2_f32_f16 %0, %2, %1, %0"
                    : "+v"(s0) : "v"(w0[p]), "s"(ls[p]));
                asm("v_dot2_f32_f16 %0, %2, %1, %0"
                    : "+v"(s1) : "v"(w1[p]), "s"(ls[p]));
                asm("v_dot2_f32_f16 %0, %2, %1, %0"
                    : "+v"(s2) : "v"(w2[p]), "s"(ls[p]));
                asm("v_dot2_f32_f16 %0, %2, %1, %0"
                    : "+v"(s3) : "v"(w3[p]), "s"(ls[p]));
            }
            const float ig = fast_sigmoid(s0);
            const float fg = fast_sigmoid(s1);
            const float gg = fast_tanh(s2);
            const float og = fast_sigmoid(s3);
            c = fmaf(fg, c, ig * gg);
            h = og * fast_tanh(c);
            // lanes >= 51: zero weights/bias -> h stays 0; contributes 0.
            pbuf[l][i] = h * fcw;  // fc staging, off critical path
        }

        // fc reduce + store (single wave: no barrier; compiler waits lgkm)
        float s2r = 0.f;
#pragma unroll
        for (int k = 0; k < HID; ++k) s2r += pbuf[k][l];
        out[b * SEQ_T + t0 + l] = s2r + fcb;  // coalesced 64-chunk

        xv = xnext;
    }
}

extern "C" void kernel_launch(void* const* d_in, const int* in_sizes, int n_in,
                              void* d_out, int out_size, void* d_ws, size_t ws_size,
                              hipStream_t stream) {
    (void)in_sizes; (void)n_in; (void)d_ws; (void)ws_size; (void)out_size;
    const float* x    = (const float*)d_in[0];
    const float* W_ih = (const float*)d_in[1];
    const float* W_hh = (const float*)d_in[2];
    const float* b_ih = (const float*)d_in[3];
    const float* b_hh = (const float*)d_in[4];
    const float* fc_w = (const float*)d_in[5];
    const float* fc_b = (const float*)d_in[6];
    float* out = (float*)d_out;

    lstm_solo_kernel<<<dim3(1024), dim3(64), 0, stream>>>(
        x, W_ih, W_hh, b_ih, b_hh, fc_w, fc_b, out);
}

// Round 11
// 611.974 us; speedup vs baseline: 1.1283x; 1.1283x over previous
//
#include <hip/hip_runtime.h>

// LSTM predictor: B=1024, T=1024, H=51, input=1. Sequential recurrence.
//
// Round 11. Cost-model correction from rounds 9/10 wall clocks:
// v_dot2_f32_f16 issues at QUARTER rate (8 cyc/wave64) on gfx950 --
// 208 dot2 x 8 = 1664 cyc/step matched the measured 1765 within 6%;
// round 6's 52-fdot2 duo matches the same model within 1%. dot2 = 0.25
// MAC/cyc/lane vs full-rate v_fmac_f32 = 0.5. So: back to fp32 fmacs.
//
// Structure (round-6 duo, proven 1-barrier/step, now fp32 end-to-end):
//  - 2 waves/block, block=batch. wave0: gates i,f; wave1: g,o.
//  - 104 fp32 weights/lane (2 gates x 52, k padded) resident -- total
//    demand ~130 = rounds 9/10's proven grant (132).
//  - h broadcast: each wave writes its own fp32 h replica to LDS, reads
//    back via 13 uniform ds_read_b128 (broadcast, conflict-free, LDS pipe
//    -- zero VALU cost, zero f16 quantization -> absmax at the 2^-10
//    floor, no double-f16 2x work).
//  - Activation exchange via parity double-buffered LDS + ONE barrier;
//    both waves then compute bit-identical c,h updates (redundant).
//  - fc output staged by wave0 in stride-65 LDS, reduced every 64 steps.

#define HID 51
#define SEQ_T 1024
#define NKW 52  // padded k per gate (k=51 -> zero weight)

static __device__ __forceinline__ float lane_bcast(float v, int lane) {
    return __int_as_float(__builtin_amdgcn_readlane(__float_as_int(v), lane));
}
static __device__ __forceinline__ float fast_sigmoid(float x) {
    float e = __builtin_amdgcn_exp2f(x * -1.44269504088896340736f);
    return __builtin_amdgcn_rcpf(1.0f + e);
}
static __device__ __forceinline__ float fast_tanh(float x) {
    float e = __builtin_amdgcn_exp2f(x * 2.88539008177792681472f);
    return 1.0f - 2.0f * __builtin_amdgcn_rcpf(e + 1.0f);
}

__global__ __launch_bounds__(128)
__attribute__((amdgpu_waves_per_eu(1, 2)))
void lstm_duo32_kernel(
    const float* __restrict__ x,      // [B, T]
    const float* __restrict__ W_ih,   // [4H, 1]
    const float* __restrict__ W_hh,   // [4H, H]
    const float* __restrict__ b_ih,   // [4H]
    const float* __restrict__ b_hh,   // [4H]
    const float* __restrict__ fc_w,   // [1, H]
    const float* __restrict__ fc_b,   // [1]
    float* __restrict__ out)          // [B, T]
{
    const int b = blockIdx.x;
    const int tid = threadIdx.x;
    const int w = tid >> 6;  // 0: gates {i,f}; 1: gates {g,o}
    const int l = tid & 63;
    const bool act = (l < HID);

    __shared__ __align__(16) float hrep[2][64];  // per-wave fp32 h replica
    __shared__ float2 axch[2][2][64];            // [parity][wave][lane]
    __shared__ float pbuf[64][65];               // fc staging (wave0 only)

    const int gA = 2 * w;      // wave0: i, wave1: g
    const int gB = 2 * w + 1;  // wave0: f, wave1: o

    // ---- per-lane fp32 weights: 2 gate-rows x 52 (padded) = 104 VGPRs ----
    float wA[NKW], wB[NKW];
#pragma unroll
    for (int k = 0; k < NKW; ++k) {
        const bool v = act && (k < HID);
        wA[k] = v ? W_hh[(gA * HID + l) * HID + k] : 0.f;
        wB[k] = v ? W_hh[(gB * HID + l) * HID + k] : 0.f;
        asm volatile("" : "+v"(wA[k]), "+v"(wB[k]));
    }
    float bA = 0.f, bB = 0.f, wxA = 0.f, wxB = 0.f, fcw = 0.f;
    if (act) {
        bA = b_ih[gA * HID + l] + b_hh[gA * HID + l];
        bB = b_ih[gB * HID + l] + b_hh[gB * HID + l];
        wxA = W_ih[gA * HID + l];
        wxB = W_ih[gB * HID + l];
        fcw = fc_w[l];
    }
    const float fcb = fc_b[0];
    float c = 0.f;

    hrep[w][l] = 0.f;  // own replica; same-wave write->read, no barrier
    __syncthreads();   // (covers the t=0 read of partner-unrelated state)

    const float4* __restrict__ hq4 = (const float4*)(&hrep[w][0]);

#pragma unroll 1
    for (int t0 = 0; t0 < SEQ_T; t0 += 64) {
        const float xv = x[b * SEQ_T + t0 + l];  // 64 steps of input

#pragma unroll 1
        for (int i = 0; i < 64; ++i) {
            const float xt = lane_bcast(xv, i);
            // 4 accumulation chains: same-chain issue gap 8 cyc >= fma lat.
            float sA0 = fmaf(xt, wxA, bA), sA1 = 0.f;
            float sB0 = fmaf(xt, wxB, bB), sB1 = 0.f;
#pragma unroll
            for (int q = 0; q < 13; ++q) {
                const float4 h4 = hq4[q];  // uniform addr -> broadcast read
                if (q & 1) {
                    sA1 = fmaf(h4.x, wA[4 * q + 0], sA1);
                    sB1 = fmaf(h4.x, wB[4 * q + 0], sB1);
                    sA1 = fmaf(h4.y, wA[4 * q + 1], sA1);
                    sB1 = fmaf(h4.y, wB[4 * q + 1], sB1);
                    sA1 = fmaf(h4.z, wA[4 * q + 2], sA1);
                    sB1 = fmaf(h4.z, wB[4 * q + 2], sB1);
                    sA1 = fmaf(h4.w, wA[4 * q + 3], sA1);
                    sB1 = fmaf(h4.w, wB[4 * q + 3], sB1);
                } else {
                    sA0 = fmaf(h4.x, wA[4 * q + 0], sA0);
                    sB0 = fmaf(h4.x, wB[4 * q + 0], sB0);
                    sA0 = fmaf(h4.y, wA[4 * q + 1], sA0);
                    sB0 = fmaf(h4.y, wB[4 * q + 1], sB0);
                    sA0 = fmaf(h4.z, wA[4 * q + 2], sA0);
                    sB0 = fmaf(h4.z, wB[4 * q + 2], sB0);
                    sA0 = fmaf(h4.w, wA[4 * q + 3], sA0);
                    sB0 = fmaf(h4.w, wB[4 * q + 3], sB0);
                }
            }
            const float sA = sA0 + sA1;
            const float sB = sB0 + sB1;

            // ---- activations (wave-uniform branch) + exchange ----
            float aA, aB;
            if (w == 0) { aA = fast_sigmoid(sA); aB = fast_sigmoid(sB); }
            else        { aA = fast_tanh(sA);    aB = fast_sigmoid(sB); }
            const int par = i & 1;
            axch[par][w][l] = make_float2(aA, aB);
            __syncthreads();  // the ONE barrier per step
            const float2 oth = axch[par][1 - w][l];

            float ig, fg, gg, og;
            if (w == 0) { ig = aA;    fg = aB;    gg = oth.x; og = oth.y; }
            else        { ig = oth.x; fg = oth.y; gg = aA;    og = aB; }

            // ---- redundant fp32 c/h update (bit-identical across waves) --
            c = fmaf(fg, c, ig * gg);
            const float hn = og * fast_tanh(c);
            // lanes >= 51: all-zero params -> s=0 -> i=f=o=0.5, g=0 ->
            // c stays 0, hn = 0. Replica pad slots stay 0 automatically.
            hrep[w][l] = hn;

            if (w == 0) pbuf[l][i] = hn * fcw;  // fc staging
        }

        if (w == 0) {
            float s2r = 0.f;
#pragma unroll
            for (int k = 0; k < HID; ++k) s2r += pbuf[k][l];
            out[b * SEQ_T + t0 + l] = s2r + fcb;  // coalesced 64-chunk
        }
    }
}

extern "C" void kernel_launch(void* const* d_in, const int* in_sizes, int n_in,
                              void* d_out, int out_size, void* d_ws, size_t ws_size,
                              hipStream_t stream) {
    (void)in_sizes; (void)n_in; (void)d_ws; (void)ws_size; (void)out_size;
    const float* x    = (const float*)d_in[0];
    const float* W_ih = (const float*)d_in[1];
    const float* W_hh = (const float*)d_in[2];
    const float* b_ih = (const float*)d_in[3];
    const float* b_hh = (const float*)d_in[4];
    const float* fc_w = (const float*)d_in[5];
    const float* fc_b = (const float*)d_in[6];
    float* out = (float*)d_out;

    lstm_duo32_kernel<<<dim3(1024), dim3(128), 0, stream>>>(
        x, W_ih, W_hh, b_ih, b_hh, fc_w, fc_b, out);
}

// Round 12
// 568.338 us; speedup vs baseline: 1.2149x; 1.0768x over previous
//
#include <hip/hip_runtime.h>

// LSTM predictor: B=1024, T=1024, H=51, input=1. Sequential recurrence.
//
// Round 12 = round 11 (duo, fp32, LDS-broadcast h, 1 barrier/step) with the
// register-residency rule learned from rounds 1-11 applied:
//   *** asm "v" operands at EVERY USE force arch-VGPR residency ***
// (rounds 9/10: asm-consumed weights -> grant 132 = demand, no spill;
//  rounds 1/2/3/5/11: fmaf-consumed weights -> AGPR spill + accvgpr_read
//  per use; round 11 grant 96 < 104-weight demand, 1598 cyc/step).
// waves_per_eu(2,2): HW pool is 512 VGPR/SIMD (m69), so 2 waves x 256 arch
// VGPRs is legal; stops the heuristic from targeting >2 waves/EU.
//
//  - 2 waves/block, block=batch. wave0: gates i,f; wave1: g,o.
//  - 104 fp32 weights/lane (2 gates x 52, k padded), asm-fmac consumed.
//  - h broadcast: per-wave fp32 LDS replica, 13 uniform ds_read_b128.
//  - Activation exchange: parity double-buffered LDS + ONE barrier;
//    redundant bit-identical c/h update on both waves.
//  - fc output staged by wave0 in stride-65 LDS, reduced every 64 steps.

#define HID 51
#define SEQ_T 1024
#define NKW 52  // padded k per gate (k=51 -> zero weight, h[51]=0)

static __device__ __forceinline__ float lane_bcast(float v, int lane) {
    return __int_as_float(__builtin_amdgcn_readlane(__float_as_int(v), lane));
}
static __device__ __forceinline__ float fast_sigmoid(float x) {
    float e = __builtin_amdgcn_exp2f(x * -1.44269504088896340736f);
    return __builtin_amdgcn_rcpf(1.0f + e);
}
static __device__ __forceinline__ float fast_tanh(float x) {
    float e = __builtin_amdgcn_exp2f(x * 2.88539008177792681472f);
    return 1.0f - 2.0f * __builtin_amdgcn_rcpf(e + 1.0f);
}

// acc += h * w, all arch VGPRs -- the use-site "v" constraints are what
// keep w resident (spilling w to AGPR would cost accvgpr_read per use).
#define FMAC(acc, h, w) \
    asm("v_fmac_f32 %0, %1, %2" : "+v"(acc) : "v"(h), "v"(w))

__global__ __launch_bounds__(128)
__attribute__((amdgpu_waves_per_eu(2, 2)))
void lstm_duo32_kernel(
    const float* __restrict__ x,      // [B, T]
    const float* __restrict__ W_ih,   // [4H, 1]
    const float* __restrict__ W_hh,   // [4H, H]
    const float* __restrict__ b_ih,   // [4H]
    const float* __restrict__ b_hh,   // [4H]
    const float* __restrict__ fc_w,   // [1, H]
    const float* __restrict__ fc_b,   // [1]
    float* __restrict__ out)          // [B, T]
{
    const int b = blockIdx.x;
    const int tid = threadIdx.x;
    const int w = tid >> 6;  // 0: gates {i,f}; 1: gates {g,o}
    const int l = tid & 63;
    const bool act = (l < HID);

    __shared__ __align__(16) float hrep[2][64];  // per-wave fp32 h replica
    __shared__ float2 axch[2][2][64];            // [parity][wave][lane]
    __shared__ float pbuf[64][65];               // fc staging (wave0 only)

    const int gA = 2 * w;      // wave0: i, wave1: g
    const int gB = 2 * w + 1;  // wave0: f, wave1: o

    // ---- per-lane fp32 weights: 2 gate-rows x 52 (padded) = 104 VGPRs ----
    float wA[NKW], wB[NKW];
#pragma unroll
    for (int k = 0; k < NKW; ++k) {
        const bool v = act && (k < HID);
        wA[k] = v ? W_hh[(gA * HID + l) * HID + k] : 0.f;
        wB[k] = v ? W_hh[(gB * HID + l) * HID + k] : 0.f;
        asm volatile("" : "+v"(wA[k]), "+v"(wB[k]));
    }
    float bA = 0.f, bB = 0.f, wxA = 0.f, wxB = 0.f, fcw = 0.f;
    if (act) {
        bA = b_ih[gA * HID + l] + b_hh[gA * HID + l];
        bB = b_ih[gB * HID + l] + b_hh[gB * HID + l];
        wxA = W_ih[gA * HID + l];
        wxB = W_ih[gB * HID + l];
        fcw = fc_w[l];
    }
    const float fcb = fc_b[0];
    float c = 0.f;

    hrep[w][l] = 0.f;  // own replica; same-wave write->read ordering via lgkm
    __syncthreads();

    const float4* __restrict__ hq4 = (const float4*)(&hrep[w][0]);

#pragma unroll 1
    for (int t0 = 0; t0 < SEQ_T; t0 += 64) {
        const float xv = x[b * SEQ_T + t0 + l];  // 64 steps of input

#pragma unroll 1
        for (int i = 0; i < 64; ++i) {
            const float xt = lane_bcast(xv, i);
            // 4 accumulator chains, interleaved A0,B0,A1,B1 -> same-chain
            // issue gap 8 cyc >= fma latency.
            float sA0 = fmaf(xt, wxA, bA), sA1 = 0.f;
            float sB0 = fmaf(xt, wxB, bB), sB1 = 0.f;
#pragma unroll
            for (int q = 0; q < 13; ++q) {
                const float4 h4 = hq4[q];  // uniform addr -> broadcast read
                FMAC(sA0, h4.x, wA[4 * q + 0]);
                FMAC(sB0, h4.x, wB[4 * q + 0]);
                FMAC(sA1, h4.y, wA[4 * q + 1]);
                FMAC(sB1, h4.y, wB[4 * q + 1]);
                FMAC(sA0, h4.z, wA[4 * q + 2]);
                FMAC(sB0, h4.z, wB[4 * q + 2]);
                FMAC(sA1, h4.w, wA[4 * q + 3]);
                FMAC(sB1, h4.w, wB[4 * q + 3]);
            }
            const float sA = sA0 + sA1;
            const float sB = sB0 + sB1;

            // ---- activations (wave-uniform branch) + exchange ----
            float aA, aB;
            if (w == 0) { aA = fast_sigmoid(sA); aB = fast_sigmoid(sB); }
            else        { aA = fast_tanh(sA);    aB = fast_sigmoid(sB); }
            const int par = i & 1;
            axch[par][w][l] = make_float2(aA, aB);
            __syncthreads();  // the ONE barrier per step
            const float2 oth = axch[par][1 - w][l];

            float ig, fg, gg, og;
            if (w == 0) { ig = aA;    fg = aB;    gg = oth.x; og = oth.y; }
            else        { ig = oth.x; fg = oth.y; gg = aA;    og = aB; }

            // ---- redundant fp32 c/h update (bit-identical across waves) --
            c = fmaf(fg, c, ig * gg);
            const float hn = og * fast_tanh(c);
            // lanes >= 51: zero params -> s=0 -> g=0 -> c=0 -> hn=0: pad ok.
            hrep[w][l] = hn;

            if (w == 0) pbuf[l][i] = hn * fcw;  // fc staging
        }

        if (w == 0) {
            float s2r = 0.f;
#pragma unroll
            for (int k = 0; k < HID; ++k) s2r += pbuf[k][l];
            out[b * SEQ_T + t0 + l] = s2r + fcb;  // coalesced 64-chunk
        }
    }
}

extern "C" void kernel_launch(void* const* d_in, const int* in_sizes, int n_in,
                              void* d_out, int out_size, void* d_ws, size_t ws_size,
                              hipStream_t stream) {
    (void)in_sizes; (void)n_in; (void)d_ws; (void)ws_size; (void)out_size;
    const float* x    = (const float*)d_in[0];
    const float* W_ih = (const float*)d_in[1];
    const float* W_hh = (const float*)d_in[2];
    const float* b_ih = (const float*)d_in[3];
    const float* b_hh = (const float*)d_in[4];
    const float* fc_w = (const float*)d_in[5];
    const float* fc_b = (const float*)d_in[6];
    float* out = (float*)d_out;

    lstm_duo32_kernel<<<dim3(1024), dim3(128), 0, stream>>>(
        x, W_ih, W_hh, b_ih, b_hh, fc_w, fc_b, out);
}